// Round 2
// baseline (190.021 us; speedup 1.0000x reference)
//
#include <hip/hip_runtime.h>
#include <hip/hip_bf16.h>
#include <stdint.h>

// Per-edge MLP  out = relu(relu([h[src],h[dst]] @ W1.T + b1) @ W2.T + b2) @ W3.T + b3
// N=100000, H=128, E=1.6M, layers 256->64->32->6, fp32 in/out.
//
// R10 == R9 resubmitted verbatim: R9's bench died to an MI355X container
// acquire failure (no compile/correctness signal). Source re-audited: all
// accesses bounds-clamped, LDS offsets b64/b128-aligned, cvt_pk asm is the
// documented gfx950 form. Theory and predictions unchanged.
//
// Pipeline:
//  0) prep_weights: W1 -> Bfrag (32KB), W2/W3 -> EFrag (5KB). The SAME Bfrag
//     bytes serve as the MFMA *A*-operand in node_gemm (A-frag and B-frag
//     have the identical lane->(idx16,k) mapping).
//  1) node_gemm (MFMA, operand-swapped): D[chan][node] = mfma(W1frag, hfrag):
//     each lane holds 4 CONSECUTIVE chans of one node -> v_cvt_pk_bf16_f32
//     pairs + global_store_dwordx2 (16 stores/wave vs 64 scalar 2B stores +
//     64 software-RNE f2bf in R8).
//  2) edge_mlp (MFMA): layer-2 operand-swapped: D[n][edge] -> lane holds
//     4 consecutive n of one edge -> cvt_pk + ds_write_b64 into the SAME
//     z-slab layout layer 3 already reads with ds_read_b128 (layer 3 unchanged).
//     bfadd2_relu: explicit <<16 / &0xffff0000 unpack (exact), f32 add+max,
//     one v_cvt_pk_bf16_f32 -- 9 inst vs ROCm's emulated __hadd2/__hmax2
//     (~20+ inst). R8 counters: VALUBusy 50%, MfmaUtil 4.5% => VALU-issue-
//     bound, so these packing cuts are the lever.
// MFMA 16x16x32_bf16 layouts (m89/m91-verified):
//   A[m=lane&15][k=(lane>>4)*8+j], B[k=(lane>>4)*8+j][n=lane&15],
//   C/D: col=lane&15, row=(lane>>4)*4+reg.  A- and B-frag lane maps are the
//   same pattern, so mfma(W,X) vs mfma(X,W) transposes D for free.

#define H 128

typedef short bf16x8 __attribute__((ext_vector_type(8)));
typedef float f32x4  __attribute__((ext_vector_type(4)));

__device__ __forceinline__ uint16_t f2bf(float f) {           // RNE fp32->bf16 (prep only)
    uint32_t u = __float_as_uint(f);
    return (uint16_t)((u + 0x7fffu + ((u >> 16) & 1u)) >> 16);
}

// HW RNE pack of two f32 into packed bf16 (1 VALU inst; no builtin on gfx950).
__device__ __forceinline__ uint32_t cvtpk(float lo, float hi) {
    uint32_t r;
    asm("v_cvt_pk_bf16_f32 %0, %1, %2" : "=v"(r) : "v"(lo), "v"(hi));
    return r;
}

// relu(a+b) on a packed bf16 pair: exact unpack via shifts, f32 math, HW RNE pack.
__device__ __forceinline__ uint32_t bfadd2_relu(uint32_t a, uint32_t b) {
    float alo = __uint_as_float(a << 16);
    float ahi = __uint_as_float(a & 0xffff0000u);
    float blo = __uint_as_float(b << 16);
    float bhi = __uint_as_float(b & 0xffff0000u);
    float slo = fmaxf(alo + blo, 0.f);
    float shi = fmaxf(ahi + bhi, 0.f);
    return cvtpk(slo, shi);
}

// ---------------- weight prep ------------------------------------------------
// Bfrag: concat-W1, 4 ktiles x 8 tiles (32 KB):
//   i = ((kt*8+ct)*64+lane)*8+j -> W1cat[n=ct*16+(lane&15)][k=kt*32+(lane>>4)*8+j]
//   (reads as B-frag with n=col, or as A-frag with m=chan -- same bytes)
// EFrag: 5 frags x 64 lanes x 8 bf16 (5 KB): W2 (4 frags) + W3 zero-padded.
__global__ void prep_weights(const float* __restrict__ W1,
                             const float* __restrict__ W2,
                             const float* __restrict__ W3,
                             uint16_t* __restrict__ Bfrag,
                             uint16_t* __restrict__ EFrag)
{
    int t = blockIdx.x * blockDim.x + threadIdx.x;
    int stride = gridDim.x * blockDim.x;
    for (int i = t; i < 4 * 8 * 64 * 8; i += stride) {
        int j    = i & 7;
        int lane = (i >> 3) & 63;
        int nt   = (i >> 9) & 7;
        int kt   = (i >> 12);
        int k = kt * 32 + (lane >> 4) * 8 + j;
        int n = nt * 16 + (lane & 15);
        float v = (n < 64) ? W1[n * 256 + k] : W1[(n - 64) * 256 + 128 + k];
        Bfrag[i] = f2bf(v);
    }
    for (int i = t; i < 5 * 64 * 8; i += stride) {
        int j    = i & 7;
        int lane = (i >> 3) & 63;
        int f    = i >> 9;
        uint16_t v;
        if (f < 4) {
            int kt = f >> 1, nt = f & 1;
            int k = kt * 32 + (lane >> 4) * 8 + j;
            int n = nt * 16 + (lane & 15);
            v = f2bf(W2[n * 64 + k]);
        } else {
            int k = (lane >> 4) * 8 + j;
            int n = lane & 15;
            v = (n < 6) ? f2bf(W3[n * 32 + k]) : (uint16_t)0;
        }
        EFrag[i] = v;
    }
}

// ---------------- per-node precompute: pre = h @ concat-W1 (+b1), MFMA ------
// Operand-swapped: D[m=chan][n=node] = mfma(A=W1frag, B=hfrag).
// Block = 4 waves = 128 nodes (2 node-tiles of 16 per wave; each W1 A-frag
// load feeds 2 MFMAs). Lane (m15,quad) ends with acc[r] = pre[node=n0+t*16+m15]
// [chan=ct*16+quad*4+r]: 4 consecutive chans -> 2x cvt_pk -> one dwordx2 store.
__global__ void __launch_bounds__(256) node_gemm(
    const float* __restrict__ h,
    const uint16_t* __restrict__ Bfrag,
    const float* __restrict__ b1,
    uint16_t* __restrict__ pre, int N)
{
    const int wave = threadIdx.x >> 6;
    const int lane = threadIdx.x & 63;
    const int n0 = (blockIdx.x * 4 + wave) * 32;
    if (n0 >= N) return;

    const int m15  = lane & 15;
    const int quad = lane >> 4;

    // B-fragments from h rows: B[k=kt*32+quad*8+j][node=m15] (fp32->bf16 RNE).
    bf16x8 hb[2][4];
#pragma unroll
    for (int t = 0; t < 2; t++) {
        int row = n0 + t * 16 + m15; if (row >= N) row = N - 1;   // stores guarded
        const float* hrow = h + (size_t)row * H + quad * 8;
#pragma unroll
        for (int kt = 0; kt < 4; kt++) {
            float4 lo = *(const float4*)(hrow + kt * 32);
            float4 hi = *(const float4*)(hrow + kt * 32 + 4);
            union { bf16x8 v; uint32_t u[4]; } B;
            B.u[0] = cvtpk(lo.x, lo.y); B.u[1] = cvtpk(lo.z, lo.w);
            B.u[2] = cvtpk(hi.x, hi.y); B.u[3] = cvtpk(hi.z, hi.w);
            hb[t][kt] = B.v;
        }
    }

    const bool ok0 = (n0 + m15) < N;
    const bool ok1 = (n0 + 16 + m15) < N;
    uint16_t* prow0 = pre + (size_t)(n0 + m15) * H;
    uint16_t* prow1 = pre + (size_t)(n0 + 16 + m15) * H;

#pragma unroll
    for (int ct = 0; ct < 8; ct++) {
        f32x4 acc0 = {0.f, 0.f, 0.f, 0.f};
        f32x4 acc1 = {0.f, 0.f, 0.f, 0.f};
#pragma unroll
        for (int kt = 0; kt < 4; kt++) {
            bf16x8 afr = *(const bf16x8*)(Bfrag + ((size_t)(kt * 8 + ct) * 64 + lane) * 8);
            acc0 = __builtin_amdgcn_mfma_f32_16x16x32_bf16(afr, hb[0][kt], acc0, 0, 0, 0);
            acc1 = __builtin_amdgcn_mfma_f32_16x16x32_bf16(afr, hb[1][kt], acc1, 0, 0, 0);
        }
        float4 bv = {0.f, 0.f, 0.f, 0.f};
        if (ct < 4) bv = *(const float4*)(b1 + ct * 16 + quad * 4);   // chans < 64 get bias
        const int off = ct * 16 + quad * 4;
        if (ok0) {
            uint32_t p0 = cvtpk(acc0[0] + bv.x, acc0[1] + bv.y);
            uint32_t p1 = cvtpk(acc0[2] + bv.z, acc0[3] + bv.w);
            *(uint2*)(prow0 + off) = uint2{p0, p1};
        }
        if (ok1) {
            uint32_t p0 = cvtpk(acc1[0] + bv.x, acc1[1] + bv.y);
            uint32_t p1 = cvtpk(acc1[2] + bv.z, acc1[3] + bv.w);
            *(uint2*)(prow1 + off) = uint2{p0, p1};
        }
    }
}

// ---------------- per-edge MLP: MFMA layers 2+3, 64 edges/wave ---------------
__global__ void __launch_bounds__(256) edge_mlp(
    const uint16_t* __restrict__ pre,
    const int* __restrict__ src, const int* __restrict__ dst,
    const uint16_t* __restrict__ EFrag,
    const float* __restrict__ b2, const float* __restrict__ b3,
    float* __restrict__ out, long E)
{
    __shared__ uint16_t zbuf[4][64 * 40];   // wave-private z slab, stride 40 halves

    const int wave = threadIdx.x >> 6;
    const int lane = threadIdx.x & 63;
    const int m15  = lane & 15;
    const int quad = lane >> 4;
    uint16_t* zw = &zbuf[wave][0];

    // Preload B-fragments (L2-hot) and biases.
    bf16x8 bL2[4], bL3;
#pragma unroll
    for (int f = 0; f < 4; f++) bL2[f] = *(const bf16x8*)(EFrag + (f * 64 + lane) * 8);
    bL3 = *(const bf16x8*)(EFrag + (4 * 64 + lane) * 8);
    // Swapped layer-2 puts channel n = nt*16 + quad*4 + r in this lane's rows.
    const float4 vb2a4 = *(const float4*)(b2 + quad * 4);
    const float4 vb2b4 = *(const float4*)(b2 + 16 + quad * 4);
    const float vb3  = (m15 < 6) ? b3[m15] : 0.f;

    const long e0 = (long)(blockIdx.x * 4 + wave) * 64;
    if (e0 >= E) return;

    // ---- issue ALL 16 gathers upfront: flat regs, 32-bit byte offsets -------
    // pre row = 256 B; lane reads 2x16B per side (halves [0,64) src / [64,128) dst).
    const char* preb = (const char*)pre;
    uint32_t oa0, oa1, oa2, oa3, ob0, ob1, ob2, ob3;
    {
        long ea = e0 + m15;           // subtile st uses edge e0+st*16+m15
        long eb = (ea + 16 < E) ? ea + 16 : E - 1;
        long ec = (ea + 32 < E) ? ea + 32 : E - 1;
        long ed = (ea + 48 < E) ? ea + 48 : E - 1;
        if (ea >= E) ea = E - 1;
        oa0 = (uint32_t)src[ea] * 256u + (uint32_t)quad * 16u;
        ob0 = (uint32_t)dst[ea] * 256u + 128u + (uint32_t)quad * 16u;
        oa1 = (uint32_t)src[eb] * 256u + (uint32_t)quad * 16u;
        ob1 = (uint32_t)dst[eb] * 256u + 128u + (uint32_t)quad * 16u;
        oa2 = (uint32_t)src[ec] * 256u + (uint32_t)quad * 16u;
        ob2 = (uint32_t)dst[ec] * 256u + 128u + (uint32_t)quad * 16u;
        oa3 = (uint32_t)src[ed] * 256u + (uint32_t)quad * 16u;
        ob3 = (uint32_t)dst[ed] * 256u + 128u + (uint32_t)quad * 16u;
    }
    uint4 a00 = *(const uint4*)(preb + oa0);
    uint4 a01 = *(const uint4*)(preb + oa0 + 64);
    uint4 b00 = *(const uint4*)(preb + ob0);
    uint4 b01 = *(const uint4*)(preb + ob0 + 64);
    uint4 a10 = *(const uint4*)(preb + oa1);
    uint4 a11 = *(const uint4*)(preb + oa1 + 64);
    uint4 b10 = *(const uint4*)(preb + ob1);
    uint4 b11 = *(const uint4*)(preb + ob1 + 64);
    uint4 a20 = *(const uint4*)(preb + oa2);
    uint4 a21 = *(const uint4*)(preb + oa2 + 64);
    uint4 b20 = *(const uint4*)(preb + ob2);
    uint4 b21 = *(const uint4*)(preb + ob2 + 64);
    uint4 a30 = *(const uint4*)(preb + oa3);
    uint4 a31 = *(const uint4*)(preb + oa3 + 64);
    uint4 b30 = *(const uint4*)(preb + ob3);
    uint4 b31 = *(const uint4*)(preb + ob3 + 64);

    // ---- layer 2 per subtile: packed-bf16 relu(a+b) -> frag -> 2x2 MFMA -----
    // Operand-swapped mfma(W2frag, X) => lane holds z[edge=m15][n=nt*16+quad*4+r]
    // (4 consecutive n) -> 2x cvt_pk + one ds_write_b64 into z-slab laid out
    // [edge][n] stride 40 halves -- exactly what layer 3's ds_read_b128 expects.
    // Write bank pattern: byte/4 = m15*20 + nt*8 + quad*2 (mod 32) -> 2-way (free).
#define DO_SUBTILE(ST, UA0, UB0, UA1, UB1)                                        \
    {                                                                             \
        union { bf16x8 v; uint32_t u[4]; } A0, A1;                                \
        A0.u[0] = bfadd2_relu(UA0.x, UB0.x);                                      \
        A0.u[1] = bfadd2_relu(UA0.y, UB0.y);                                      \
        A0.u[2] = bfadd2_relu(UA0.z, UB0.z);                                      \
        A0.u[3] = bfadd2_relu(UA0.w, UB0.w);                                      \
        A1.u[0] = bfadd2_relu(UA1.x, UB1.x);                                      \
        A1.u[1] = bfadd2_relu(UA1.y, UB1.y);                                      \
        A1.u[2] = bfadd2_relu(UA1.z, UB1.z);                                      \
        A1.u[3] = bfadd2_relu(UA1.w, UB1.w);                                      \
        _Pragma("unroll")                                                         \
        for (int nt = 0; nt < 2; nt++) {                                          \
            f32x4 acc = {0.f, 0.f, 0.f, 0.f};                                     \
            acc = __builtin_amdgcn_mfma_f32_16x16x32_bf16(bL2[nt], A0.v, acc, 0, 0, 0); \
            acc = __builtin_amdgcn_mfma_f32_16x16x32_bf16(bL2[2 + nt], A1.v, acc, 0, 0, 0); \
            const float4 bv = nt ? vb2b4 : vb2a4;                                 \
            uint32_t p0 = cvtpk(fmaxf(acc[0] + bv.x, 0.f), fmaxf(acc[1] + bv.y, 0.f)); \
            uint32_t p1 = cvtpk(fmaxf(acc[2] + bv.z, 0.f), fmaxf(acc[3] + bv.w, 0.f)); \
            *(uint2*)(zw + ((ST) * 16 + m15) * 40 + nt * 16 + quad * 4) = uint2{p0, p1}; \
        }                                                                         \
    }

    DO_SUBTILE(0, a00, b00, a01, b01)
    DO_SUBTILE(1, a10, b10, a11, b11)
    DO_SUBTILE(2, a20, b20, a21, b21)
    DO_SUBTILE(3, a30, b30, a31, b31)
#undef DO_SUBTILE

    // ---- layer 3: LDS A-frags -> 1 MFMA per subtile -------------------------
#pragma unroll
    for (int st = 0; st < 4; st++) {
        bf16x8 a3 = *(const bf16x8*)(zw + (st * 16 + m15) * 40 + quad * 8);
        f32x4 o = {0.f, 0.f, 0.f, 0.f};
        o = __builtin_amdgcn_mfma_f32_16x16x32_bf16(a3, bL3, o, 0, 0, 0);
        if (m15 < 6) {
#pragma unroll
            for (int r = 0; r < 4; r++) {
                long e = e0 + st * 16 + quad * 4 + r;
                if (e < E) out[e * 6 + m15] = o[r] + vb3;
            }
        }
    }
}

extern "C" void kernel_launch(void* const* d_in, const int* in_sizes, int n_in,
                              void* d_out, int out_size, void* d_ws, size_t ws_size,
                              hipStream_t stream) {
    const float* h   = (const float*)d_in[0];
    const int*   src = (const int*)d_in[1];
    const int*   dst = (const int*)d_in[2];
    const float* W1  = (const float*)d_in[3];
    const float* b1  = (const float*)d_in[4];
    const float* W2  = (const float*)d_in[5];
    const float* b2  = (const float*)d_in[6];
    const float* W3  = (const float*)d_in[7];
    const float* b3  = (const float*)d_in[8];

    const int  N = in_sizes[0] / H;     // 100000
    const long E = in_sizes[1];         // 1600000

    char* ws = (char*)d_ws;
    uint16_t* Bfrag = (uint16_t*)ws;                 // 32 KiB
    uint16_t* EFrag = (uint16_t*)(ws + 64 * 1024);   // 5 KiB
    uint16_t* pre   = (uint16_t*)(ws + 128 * 1024);  // N*128*2 = 25.6 MB (bf16)

    prep_weights<<<64, 256, 0, stream>>>(W1, W2, W3, Bfrag, EFrag);
    node_gemm<<<(N + 127) / 128, 256, 0, stream>>>(h, Bfrag, b1, pre, N);
    const int eblocks = (int)((E + 255) / 256);      // 4 waves x 64 edges per block
    edge_mlp<<<eblocks, 256, 0, stream>>>(pre, src, dst, EFrag, b2, b3,
                                          (float*)d_out, E);
}